// Round 1
// baseline (1740.221 us; speedup 1.0000x reference)
//
#include <hip/hip_runtime.h>
#include <math.h>

#define NPIX 4096   // H*W
#define CCH  256    // channels (C_IN == C_OUT)
#define NBATCH 4

// ---------------------------------------------------------------------------
// conv1x1: out[b][o][n] = act( sum_c W[o][c] * x[b][c][n] + bias[o] )
// grid: (NPIX/64, CCH/64, B), block 256, 64x64 tile, 4x4 micro-tile.
// ---------------------------------------------------------------------------
template<bool RELU>
__global__ __launch_bounds__(256) void conv1x1_k(
    const float* __restrict__ x, const float* __restrict__ W,
    const float* __restrict__ bias, float* __restrict__ out)
{
  const int nb = blockIdx.x * 64;
  const int ob = blockIdx.y * 64;
  const int b  = blockIdx.z;
  const int t  = threadIdx.x;
  const int ty = t >> 4;   // 0..15 -> o micro-row
  const int tx = t & 15;   // 0..15 -> n micro-col

  __shared__ float Ws[64][260];   // [o][c], pad 260 (1040B = 65*16, f4-aligned)
  __shared__ float Xs[32][64];    // [c][n]

  // stage W tile [64 o][256 c] once
  #pragma unroll
  for (int k = 0; k < 16; ++k) {
    int e = t + 256 * k;          // f4 index: 64 rows x 64 f4-cols
    int o = e >> 6, c4 = e & 63;
    *reinterpret_cast<float4*>(&Ws[o][c4 * 4]) =
        *reinterpret_cast<const float4*>(&W[(size_t)(ob + o) * CCH + c4 * 4]);
  }

  float acc[4][4] = {};
  for (int kc = 0; kc < CCH; kc += 32) {
    __syncthreads();   // protects Xs overwrite (and first-iter Ws visibility via next sync)
    #pragma unroll
    for (int k = 0; k < 2; ++k) {
      int e = t + 256 * k;        // f4 index: 32 rows x 16 f4-cols
      int cc = e >> 4, n4 = e & 15;
      *reinterpret_cast<float4*>(&Xs[cc][n4 * 4]) =
          *reinterpret_cast<const float4*>(
              &x[((size_t)b * CCH + kc + cc) * NPIX + nb + n4 * 4]);
    }
    __syncthreads();
    #pragma unroll
    for (int k4 = 0; k4 < 8; ++k4) {
      alignas(16) float wv[4][4];
      alignas(16) float xv[4][4];
      #pragma unroll
      for (int i = 0; i < 4; ++i)
        *reinterpret_cast<float4*>(wv[i]) =
            *reinterpret_cast<const float4*>(&Ws[4 * ty + i][kc + k4 * 4]);
      #pragma unroll
      for (int u = 0; u < 4; ++u)
        *reinterpret_cast<float4*>(xv[u]) =
            *reinterpret_cast<const float4*>(&Xs[k4 * 4 + u][4 * tx]);
      #pragma unroll
      for (int i = 0; i < 4; ++i)
        #pragma unroll
        for (int u = 0; u < 4; ++u)
          #pragma unroll
          for (int j = 0; j < 4; ++j)
            acc[i][j] = fmaf(wv[i][u], xv[u][j], acc[i][j]);
    }
  }

  #pragma unroll
  for (int i = 0; i < 4; ++i) {
    const float bo = bias[ob + 4 * ty + i];
    float4 r;
    float v0 = acc[i][0] + bo, v1 = acc[i][1] + bo,
          v2 = acc[i][2] + bo, v3 = acc[i][3] + bo;
    if (RELU) {
      v0 = fmaxf(v0, 0.f); v1 = fmaxf(v1, 0.f);
      v2 = fmaxf(v2, 0.f); v3 = fmaxf(v3, 0.f);
    }
    r.x = v0; r.y = v1; r.z = v2; r.w = v3;
    *reinterpret_cast<float4*>(
        &out[((size_t)b * CCH + ob + 4 * ty + i) * NPIX + nb + 4 * tx]) = r;
  }
}

// ---------------------------------------------------------------------------
// Flash attention (fp32, unscaled scores, softmax over keys):
//   av[b][c][q] = sum_m softmax_m(sum_c' Q[c'][q] K[c'][m]) * V[c][m]
// Block: 512 threads, one 64-query tile; loops 64 key-tiles of 64.
// S mapping : q = 2*ty + i (ty=t/16, i 0..1), m = 4*tx + j (tx=t%16, j 0..3)
// AV mapping: co = 32*r + ty (r 0..7),       q = 4*tx + jq (jq 0..3)
// Online softmax state (m,l) lives in registers, replicated across the 16 tx
// lanes of each q-row; butterfly __shfl_xor keeps replicas identical.
// ---------------------------------------------------------------------------
__global__ __launch_bounds__(512) void attn_k(
    const float* __restrict__ Q, const float* __restrict__ K,
    const float* __restrict__ V, float* __restrict__ av)
{
  const int b  = blockIdx.y;
  const int qb = blockIdx.x * 64;
  const int t  = threadIdx.x;
  const int ty = t >> 4;   // 0..31
  const int tx = t & 15;   // 0..15

  __shared__ float Qs[64][64];      // [c][q]
  __shared__ float Ks[64][64];      // [c][m]
  __shared__ float Ps[64][65];      // [q][m], pad 65 -> 2-way-max conflicts
  __shared__ float Vs[256][20];     // [co][mm], pad 20 keeps f4 alignment
  __shared__ float alphaArr[64];
  __shared__ float lrow[64];

  const float* Qb = Q + (size_t)b * CCH * NPIX;
  const float* Kb = K + (size_t)b * CCH * NPIX;
  const float* Vb = V + (size_t)b * CCH * NPIX;

  float Oacc[8][4] = {};
  float mrun0 = -INFINITY, mrun1 = -INFINITY;
  float lrun0 = 0.f, lrun1 = 0.f;

  for (int mt = 0; mt < 64; ++mt) {
    const int mb = mt * 64;
    float S0[4] = {}, S1[4] = {};

    // ---- S = Q^T K over C=256 in 4 k-steps of 64 ----
    for (int kc = 0; kc < CCH; kc += 64) {
      __syncthreads();
      #pragma unroll
      for (int k = 0; k < 2; ++k) {
        int e = t + 512 * k;        // f4 idx: 64 rows x 16 f4-cols
        int cc = e >> 4, c4 = e & 15;
        *reinterpret_cast<float4*>(&Qs[cc][c4 * 4]) =
            *reinterpret_cast<const float4*>(&Qb[(size_t)(kc + cc) * NPIX + qb + c4 * 4]);
        *reinterpret_cast<float4*>(&Ks[cc][c4 * 4]) =
            *reinterpret_cast<const float4*>(&Kb[(size_t)(kc + cc) * NPIX + mb + c4 * 4]);
      }
      __syncthreads();
      #pragma unroll
      for (int kk = 0; kk < 64; ++kk) {
        const float a0 = Qs[kk][2 * ty];
        const float a1 = Qs[kk][2 * ty + 1];
        alignas(16) float bk[4];
        *reinterpret_cast<float4*>(bk) =
            *reinterpret_cast<const float4*>(&Ks[kk][4 * tx]);
        #pragma unroll
        for (int j = 0; j < 4; ++j) {
          S0[j] = fmaf(a0, bk[j], S0[j]);
          S1[j] = fmaf(a1, bk[j], S1[j]);
        }
      }
    }

    // ---- online softmax (registers + shfl), write P and alpha ----
    float al0, al1, p0[4], p1[4];
    {
      float rmax = fmaxf(fmaxf(S0[0], S0[1]), fmaxf(S0[2], S0[3]));
      #pragma unroll
      for (int mk = 1; mk <= 8; mk <<= 1) rmax = fmaxf(rmax, __shfl_xor(rmax, mk));
      const float mnew = fmaxf(mrun0, rmax);
      al0 = __expf(mrun0 - mnew); mrun0 = mnew;
      float rs = 0.f;
      #pragma unroll
      for (int j = 0; j < 4; ++j) { p0[j] = __expf(S0[j] - mnew); rs += p0[j]; }
      #pragma unroll
      for (int mk = 1; mk <= 8; mk <<= 1) rs += __shfl_xor(rs, mk);
      lrun0 = lrun0 * al0 + rs;
    }
    {
      float rmax = fmaxf(fmaxf(S1[0], S1[1]), fmaxf(S1[2], S1[3]));
      #pragma unroll
      for (int mk = 1; mk <= 8; mk <<= 1) rmax = fmaxf(rmax, __shfl_xor(rmax, mk));
      const float mnew = fmaxf(mrun1, rmax);
      al1 = __expf(mrun1 - mnew); mrun1 = mnew;
      float rs = 0.f;
      #pragma unroll
      for (int j = 0; j < 4; ++j) { p1[j] = __expf(S1[j] - mnew); rs += p1[j]; }
      #pragma unroll
      for (int mk = 1; mk <= 8; mk <<= 1) rs += __shfl_xor(rs, mk);
      lrun1 = lrun1 * al1 + rs;
    }
    #pragma unroll
    for (int j = 0; j < 4; ++j) {
      Ps[2 * ty][4 * tx + j]     = p0[j];
      Ps[2 * ty + 1][4 * tx + j] = p1[j];
    }
    if (tx == 0) { alphaArr[2 * ty] = al0; alphaArr[2 * ty + 1] = al1; }
    __syncthreads();

    // ---- rescale O accumulators by alpha[q] (AV mapping: q = 4*tx+jq) ----
    float alq[4];
    #pragma unroll
    for (int jq = 0; jq < 4; ++jq) alq[jq] = alphaArr[4 * tx + jq];
    #pragma unroll
    for (int r = 0; r < 8; ++r)
      #pragma unroll
      for (int jq = 0; jq < 4; ++jq) Oacc[r][jq] *= alq[jq];

    // ---- O += P * V over this 64-key tile, staged 16 keys at a time ----
    for (int ms = 0; ms < 4; ++ms) {
      __syncthreads();
      #pragma unroll
      for (int k = 0; k < 2; ++k) {
        int e = t + 512 * k;       // f4: co = e>>2 (0..255), m4 = e&3
        int co = e >> 2, m4 = e & 3;
        *reinterpret_cast<float4*>(&Vs[co][m4 * 4]) =
            *reinterpret_cast<const float4*>(
                &Vb[(size_t)co * NPIX + mb + ms * 16 + m4 * 4]);
      }
      __syncthreads();
      #pragma unroll
      for (int m4 = 0; m4 < 4; ++m4) {
        alignas(16) float vv[8][4];
        #pragma unroll
        for (int r = 0; r < 8; ++r)
          *reinterpret_cast<float4*>(vv[r]) =
              *reinterpret_cast<const float4*>(&Vs[32 * r + ty][m4 * 4]);
        float pj[4][4];
        #pragma unroll
        for (int jq = 0; jq < 4; ++jq)
          #pragma unroll
          for (int u = 0; u < 4; ++u)
            pj[jq][u] = Ps[4 * tx + jq][ms * 16 + m4 * 4 + u];
        #pragma unroll
        for (int r = 0; r < 8; ++r)
          #pragma unroll
          for (int jq = 0; jq < 4; ++jq)
            #pragma unroll
            for (int u = 0; u < 4; ++u)
              Oacc[r][jq] = fmaf(vv[r][u], pj[jq][u], Oacc[r][jq]);
      }
    }
  }

  // ---- epilogue: divide by l and store av[b][co][qb+q] ----
  __syncthreads();
  if (tx == 0) { lrow[2 * ty] = lrun0; lrow[2 * ty + 1] = lrun1; }
  __syncthreads();
  float linv[4];
  #pragma unroll
  for (int jq = 0; jq < 4; ++jq) linv[jq] = 1.0f / lrow[4 * tx + jq];
  #pragma unroll
  for (int r = 0; r < 8; ++r) {
    float4 o;
    o.x = Oacc[r][0] * linv[0];
    o.y = Oacc[r][1] * linv[1];
    o.z = Oacc[r][2] * linv[2];
    o.w = Oacc[r][3] * linv[3];
    *reinterpret_cast<float4*>(
        &av[((size_t)b * CCH + 32 * r + ty) * NPIX + qb + 4 * tx]) = o;
  }
}

// ---------------------------------------------------------------------------
extern "C" void kernel_launch(void* const* d_in, const int* in_sizes, int n_in,
                              void* d_out, int out_size, void* d_ws, size_t ws_size,
                              hipStream_t stream) {
  const float* x_q  = (const float*)d_in[0];   // query_input  [4,256,64,64]
  const float* x_kv = (const float*)d_in[1];   // key_value_input
  const float* Wq = (const float*)d_in[2];
  const float* bq = (const float*)d_in[3];
  const float* Wk = (const float*)d_in[4];
  const float* bk = (const float*)d_in[5];
  const float* Wv = (const float*)d_in[6];
  const float* bv = (const float*)d_in[7];
  const float* W1 = (const float*)d_in[8];
  const float* b1 = (const float*)d_in[9];
  const float* W2 = (const float*)d_in[10];
  const float* b2 = (const float*)d_in[11];
  float* out = (float*)d_out;

  const size_t buf = (size_t)NBATCH * CCH * NPIX;   // 4.19M floats = 16.8 MB
  float* Qp  = (float*)d_ws;
  float* Kp  = Qp + buf;
  float* Vp  = Kp + buf;
  float* AVp = Vp + buf;
  float* HIDp = Qp;   // Q dead after attention; reuse its buffer for hid

  dim3 cgrid(NPIX / 64, CCH / 64, NBATCH);
  dim3 cblk(256);
  hipLaunchKernelGGL((conv1x1_k<false>), cgrid, cblk, 0, stream, x_q,  Wq, bq, Qp);
  hipLaunchKernelGGL((conv1x1_k<false>), cgrid, cblk, 0, stream, x_kv, Wk, bk, Kp);
  hipLaunchKernelGGL((conv1x1_k<false>), cgrid, cblk, 0, stream, x_kv, Wv, bv, Vp);

  dim3 agrid(NPIX / 64, NBATCH);
  hipLaunchKernelGGL(attn_k, agrid, dim3(512), 0, stream, Qp, Kp, Vp, AVp);

  hipLaunchKernelGGL((conv1x1_k<true>),  cgrid, cblk, 0, stream, AVp, W1, b1, HIDp);
  hipLaunchKernelGGL((conv1x1_k<false>), cgrid, cblk, 0, stream, HIDp, W2, b2, out);
}

// Round 2
// 566.907 us; speedup vs baseline: 3.0697x; 3.0697x over previous
//
#include <hip/hip_runtime.h>
#include <math.h>

#define CCH 256
#define NPIX 4096
#define NB 4

typedef float f32x4 __attribute__((ext_vector_type(4)));
typedef short s16x8 __attribute__((ext_vector_type(8)));
typedef unsigned short u16;
typedef unsigned int u32;

__device__ __forceinline__ u16 f2bf(float f) {
  u32 u = __float_as_uint(f);
  u = (u + 0x7fffu + ((u >> 16) & 1u)) >> 16;   // RNE to bf16
  return (u16)u;
}
__device__ __forceinline__ float bf2f(u16 h) {
  return __uint_as_float(((u32)h) << 16);
}
__device__ __forceinline__ u32 shflu(u32 v, int src) {
  return (u32)__shfl((int)v, src, 64);
}

using gas_t = const __attribute__((address_space(1))) void*;
using las_t = __attribute__((address_space(3))) void*;
__device__ __forceinline__ void gl2lds16(const void* g, void* l) {
  __builtin_amdgcn_global_load_lds((gas_t)g, (las_t)l, 16, 0, 0);
}

// ---------------------------------------------------------------------------
// conv1x1 64x64 tile. MODE 0: fp32 [b][o][n]; MODE 1: bf16 hi/lo [b][o][n];
// MODE 2: bf16 hi/lo TRANSPOSED [b][n][o] (LDS-transpose epilogue).
// ---------------------------------------------------------------------------
template<int MODE, bool RELU>
__global__ __launch_bounds__(256) void conv1x1_k(
    const float* __restrict__ x, const float* __restrict__ W,
    const float* __restrict__ bias, void* __restrict__ outA, void* __restrict__ outB)
{
  const int nb = blockIdx.x * 64;
  const int ob = blockIdx.y * 64;
  const int b  = blockIdx.z;
  const int t  = threadIdx.x;
  const int ty = t >> 4;
  const int tx = t & 15;

  __shared__ float Ws[64][260];
  __shared__ float Xs[32][64];

  #pragma unroll
  for (int k = 0; k < 16; ++k) {
    int e = t + 256 * k;
    int o = e >> 6, c4 = e & 63;
    *reinterpret_cast<float4*>(&Ws[o][c4 * 4]) =
        *reinterpret_cast<const float4*>(&W[(size_t)(ob + o) * CCH + c4 * 4]);
  }

  float acc[4][4] = {};
  for (int kc = 0; kc < CCH; kc += 32) {
    __syncthreads();
    #pragma unroll
    for (int k = 0; k < 2; ++k) {
      int e = t + 256 * k;
      int cc = e >> 4, n4 = e & 15;
      *reinterpret_cast<float4*>(&Xs[cc][n4 * 4]) =
          *reinterpret_cast<const float4*>(
              &x[((size_t)b * CCH + kc + cc) * NPIX + nb + n4 * 4]);
    }
    __syncthreads();
    #pragma unroll
    for (int k4 = 0; k4 < 8; ++k4) {
      alignas(16) float wv[4][4];
      alignas(16) float xv[4][4];
      #pragma unroll
      for (int i = 0; i < 4; ++i)
        *reinterpret_cast<float4*>(wv[i]) =
            *reinterpret_cast<const float4*>(&Ws[4 * ty + i][kc + k4 * 4]);
      #pragma unroll
      for (int u = 0; u < 4; ++u)
        *reinterpret_cast<float4*>(xv[u]) =
            *reinterpret_cast<const float4*>(&Xs[k4 * 4 + u][4 * tx]);
      #pragma unroll
      for (int i = 0; i < 4; ++i)
        #pragma unroll
        for (int u = 0; u < 4; ++u)
          #pragma unroll
          for (int j = 0; j < 4; ++j)
            acc[i][j] = fmaf(wv[i][u], xv[u][j], acc[i][j]);
    }
  }

  if (MODE == 0) {
    float* out = (float*)outA;
    #pragma unroll
    for (int i = 0; i < 4; ++i) {
      const float bo = bias[ob + 4 * ty + i];
      float v0 = acc[i][0] + bo, v1 = acc[i][1] + bo,
            v2 = acc[i][2] + bo, v3 = acc[i][3] + bo;
      if (RELU) {
        v0 = fmaxf(v0, 0.f); v1 = fmaxf(v1, 0.f);
        v2 = fmaxf(v2, 0.f); v3 = fmaxf(v3, 0.f);
      }
      float4 r; r.x = v0; r.y = v1; r.z = v2; r.w = v3;
      *reinterpret_cast<float4*>(
          &out[((size_t)b * CCH + ob + 4 * ty + i) * NPIX + nb + 4 * tx]) = r;
    }
  } else if (MODE == 1) {
    u16* oh = (u16*)outA; u16* ol = (u16*)outB;
    #pragma unroll
    for (int i = 0; i < 4; ++i) {
      const float bo = bias[ob + 4 * ty + i];
      ushort4 hv, lv;
      u16 hj[4], lj[4];
      #pragma unroll
      for (int j = 0; j < 4; ++j) {
        float v = acc[i][j] + bo;
        u16 h = f2bf(v);
        hj[j] = h; lj[j] = f2bf(v - bf2f(h));
      }
      hv.x = hj[0]; hv.y = hj[1]; hv.z = hj[2]; hv.w = hj[3];
      lv.x = lj[0]; lv.y = lj[1]; lv.z = lj[2]; lv.w = lj[3];
      size_t base = ((size_t)b * CCH + ob + 4 * ty + i) * NPIX + nb + 4 * tx;
      *reinterpret_cast<ushort4*>(&oh[base]) = hv;
      *reinterpret_cast<ushort4*>(&ol[base]) = lv;
    }
  } else {
    // transpose epilogue: reuse Ws as u32 tile [n_local 64][o_local 68-padded]
    __syncthreads();
    u32* T = reinterpret_cast<u32*>(&Ws[0][0]);
    #pragma unroll
    for (int i = 0; i < 4; ++i) {
      const float bo = bias[ob + 4 * ty + i];
      #pragma unroll
      for (int j = 0; j < 4; ++j) {
        float v = acc[i][j] + bo;
        u16 h = f2bf(v);
        u16 l = f2bf(v - bf2f(h));
        T[(4 * tx + j) * 68 + 4 * ty + i] = (u32)h | ((u32)l << 16);
      }
    }
    __syncthreads();
    u16* oh = (u16*)outA; u16* ol = (u16*)outB;
    #pragma unroll
    for (int k = 0; k < 4; ++k) {
      int e = t * 4 + 1024 * k;
      int nl = e >> 6, c0 = e & 63;
      u32 w0 = T[nl * 68 + c0 + 0], w1 = T[nl * 68 + c0 + 1];
      u32 w2 = T[nl * 68 + c0 + 2], w3 = T[nl * 68 + c0 + 3];
      ushort4 hv, lv;
      hv.x = (u16)w0; hv.y = (u16)w1; hv.z = (u16)w2; hv.w = (u16)w3;
      lv.x = (u16)(w0 >> 16); lv.y = (u16)(w1 >> 16);
      lv.z = (u16)(w2 >> 16); lv.w = (u16)(w3 >> 16);
      size_t base = ((size_t)b * NPIX + nb + nl) * CCH + ob + c0;
      *reinterpret_cast<ushort4*>(&oh[base]) = hv;
      *reinterpret_cast<ushort4*>(&ol[base]) = lv;
    }
  }
}

// ---------------------------------------------------------------------------
// MFMA flash attention, 3-term bf16 split (fp32-grade accuracy).
// Block 512 thr = 8 waves: wid = g (q-group of 16) + 4*par (key half of 32).
// Per 64-key tile: QK^T = K^T(A) x Q(B) -> S^T; in-register online softmax
// (each wave independent over its key half, merged in epilogue); P routed to
// PV B-frags via 16 shfls; PV = V(A) x P^T(B). K/V double-buffered LDS via
// global_load_lds w16, XOR chunk swizzle (inverse-swizzled source).
// ---------------------------------------------------------------------------
__global__ __launch_bounds__(512) void attn_mfma(
    const u16* __restrict__ Qth, const u16* __restrict__ Qtl,   // [b][n][c]
    const u16* __restrict__ Kth, const u16* __restrict__ Ktl,   // [b][n][c]
    const u16* __restrict__ Vh,  const u16* __restrict__ Vl,    // [b][c][n]
    float* __restrict__ av)                                      // [b][c][n]
{
  __shared__ alignas(16) u16 sK[2][64 * 256];    // 64 KB  (h,l)
  __shared__ alignas(16) u16 sV[2][256 * 64];    // 64 KB  (h,l)
  __shared__ float sMm[2][64];
  __shared__ float sMl[2][64];

  const int b    = blockIdx.y;
  const int qb   = blockIdx.x * 64;
  const int tid  = threadIdx.x;
  const int wid  = tid >> 6;
  const int g    = wid & 3;     // q-group (16 queries)
  const int par  = wid >> 2;    // key half (32 keys of each 64-tile)
  const int lane = tid & 63;
  const int gg   = lane >> 4;
  const int x    = lane & 15;

  // resident Q fragments: B[k=c][col=q], lane: q=x, c = kc*32 + gg*8 + i
  s16x8 qh[8], ql[8];
  {
    const u16* qhp = Qth + ((size_t)b * NPIX + qb + g * 16 + x) * CCH;
    const u16* qlp = Qtl + ((size_t)b * NPIX + qb + g * 16 + x) * CCH;
    #pragma unroll
    for (int kc = 0; kc < 8; ++kc) {
      qh[kc] = *reinterpret_cast<const s16x8*>(qhp + kc * 32 + gg * 8);
      ql[kc] = *reinterpret_cast<const s16x8*>(qlp + kc * 32 + gg * 8);
    }
  }

  // staging maps (linear LDS dest; source chunk pre-swizzled, rule #21)
  int kSrc[4], kDst[4], vSrc[4], vDst[4];
  #pragma unroll
  for (int r = 0; r < 4; ++r) {
    int e = tid + 512 * r;
    int m = e >> 5, ch = e & 31;              // K: 64 rows x 32 chunks
    kSrc[r] = m * CCH + ((ch ^ (m & 7)) * 8);
    kDst[r] = e * 8;
    int c = e >> 3, c2 = e & 7;               // V: 256 rows x 8 chunks
    vSrc[r] = c * NPIX + ((c2 ^ (c & 7)) * 8);
    vDst[r] = e * 8;
  }
  const u16* KthB = Kth + (size_t)b * NPIX * CCH;
  const u16* KtlB = Ktl + (size_t)b * NPIX * CCH;
  const u16* VhB  = Vh  + (size_t)b * CCH * NPIX;
  const u16* VlB  = Vl  + (size_t)b * CCH * NPIX;

  f32x4 Oacc[16];
  #pragma unroll
  for (int i = 0; i < 16; ++i) Oacc[i] = f32x4{0.f, 0.f, 0.f, 0.f};
  float m_run = -INFINITY, l_run = 0.f;

  // prologue: stage tile 0 of K and V
  #pragma unroll
  for (int r = 0; r < 4; ++r) {
    gl2lds16(KthB + kSrc[r], &sK[0][kDst[r]]);
    gl2lds16(KtlB + kSrc[r], &sK[1][kDst[r]]);
    gl2lds16(VhB  + vSrc[r], &sV[0][vDst[r]]);
    gl2lds16(VlB  + vSrc[r], &sV[1][vDst[r]]);
  }
  __syncthreads();

  for (int mt = 0; mt < 64; ++mt) {
    // ---- QK^T: St[msub] = S^T tile, rows=keys, col=q=x ----
    f32x4 St[2];
    St[0] = f32x4{0.f, 0.f, 0.f, 0.f};
    St[1] = f32x4{0.f, 0.f, 0.f, 0.f};
    #pragma unroll
    for (int msub = 0; msub < 2; ++msub) {
      const int m  = par * 32 + msub * 16 + x;   // A-row = key (lane&15)
      const int rb = m * CCH;
      #pragma unroll
      for (int kc = 0; kc < 8; ++kc) {
        const int ch = ((kc * 4 + gg) ^ (x & 7)) * 8;   // m&7 == x&7
        s16x8 ah = *reinterpret_cast<const s16x8*>(&sK[0][rb + ch]);
        s16x8 al = *reinterpret_cast<const s16x8*>(&sK[1][rb + ch]);
        St[msub] = __builtin_amdgcn_mfma_f32_16x16x32_bf16(ah, qh[kc], St[msub], 0, 0, 0);
        St[msub] = __builtin_amdgcn_mfma_f32_16x16x32_bf16(ah, ql[kc], St[msub], 0, 0, 0);
        St[msub] = __builtin_amdgcn_mfma_f32_16x16x32_bf16(al, qh[kc], St[msub], 0, 0, 0);
      }
    }
    __syncthreads();            // K consumed; V(t) loads drained

    if (mt + 1 < 64) {          // prefetch K(t+1), overlaps softmax+PV
      const size_t ko = (size_t)(mt + 1) * 64 * CCH;
      #pragma unroll
      for (int r = 0; r < 4; ++r) {
        gl2lds16(KthB + ko + kSrc[r], &sK[0][kDst[r]]);
        gl2lds16(KtlB + ko + kSrc[r], &sK[1][kDst[r]]);
      }
    }

    // ---- online softmax (wave-local; keys = par-half) ----
    // lane holds S[q=x][key = msub*16 + gg*4 + r] (D-layout)
    float vmax = fmaxf(fmaxf(fmaxf(St[0][0], St[0][1]), fmaxf(St[0][2], St[0][3])),
                       fmaxf(fmaxf(St[1][0], St[1][1]), fmaxf(St[1][2], St[1][3])));
    vmax = fmaxf(vmax, __shfl_xor(vmax, 16, 64));
    vmax = fmaxf(vmax, __shfl_xor(vmax, 32, 64));
    const float mnew  = fmaxf(m_run, vmax);
    const float alpha = __expf(m_run - mnew);
    float p[2][4];
    float ps = 0.f;
    #pragma unroll
    for (int ms = 0; ms < 2; ++ms)
      #pragma unroll
      for (int r = 0; r < 4; ++r) {
        p[ms][r] = __expf(St[ms][r] - mnew);
        ps += p[ms][r];
      }
    ps += __shfl_xor(ps, 16, 64);
    ps += __shfl_xor(ps, 32, 64);
    l_run = l_run * alpha + ps;
    m_run = mnew;
    #pragma unroll
    for (int i = 0; i < 16; ++i) Oacc[i] *= alpha;

    // ---- pack P hi/lo and route to PV B-frag layout via shfl ----
    u32 Pph[2][2], Ppl[2][2];
    #pragma unroll
    for (int ms = 0; ms < 2; ++ms)
      #pragma unroll
      for (int w = 0; w < 2; ++w) {
        float v0 = p[ms][2 * w], v1 = p[ms][2 * w + 1];
        u16 h0 = f2bf(v0), h1 = f2bf(v1);
        u16 l0 = f2bf(v0 - bf2f(h0)), l1 = f2bf(v1 - bf2f(h1));
        Pph[ms][w] = (u32)h0 | ((u32)h1 << 16);
        Ppl[ms][w] = (u32)l0 | ((u32)l1 << 16);
      }
    // B[k = gg*8+i][q=x]: element i from lane gg' = 2*(gg&1)+(i>>2),
    // producer reg msub = gg>>1, word = (i&3)>>1
    const int src0 = ((gg & 1) * 2) * 16 + x;
    const int src1 = src0 + 16;
    const bool sel = (gg >> 1) != 0;
    union { u32 u[4]; s16x8 v; } bh, bl;
    {
      u32 a0 = shflu(Pph[0][0], src0), a1 = shflu(Pph[1][0], src0);
      u32 b0 = shflu(Pph[0][1], src0), b1 = shflu(Pph[1][1], src0);
      u32 c0 = shflu(Pph[0][0], src1), c1 = shflu(Pph[1][0], src1);
      u32 d0 = shflu(Pph[0][1], src1), d1 = shflu(Pph[1][1], src1);
      bh.u[0] = sel ? a1 : a0;
      bh.u[1] = sel ? b1 : b0;
      bh.u[2] = sel ? c1 : c0;
      bh.u[3] = sel ? d1 : d0;
      u32 e0 = shflu(Ppl[0][0], src0), e1 = shflu(Ppl[1][0], src0);
      u32 f0 = shflu(Ppl[0][1], src0), f1 = shflu(Ppl[1][1], src0);
      u32 g0 = shflu(Ppl[0][0], src1), g1 = shflu(Ppl[1][0], src1);
      u32 h0 = shflu(Ppl[0][1], src1), h1 = shflu(Ppl[1][1], src1);
      bl.u[0] = sel ? e1 : e0;
      bl.u[1] = sel ? f1 : f0;
      bl.u[2] = sel ? g1 : g0;
      bl.u[3] = sel ? h1 : h0;
    }

    // ---- PV: Oacc[cs] += V(A) x P^T(B) over this wave's 32 keys ----
    #pragma unroll
    for (int cs = 0; cs < 16; ++cs) {
      const int c  = cs * 16 + x;               // A-row = channel (lane&15)
      const int rb = c * 64;
      const int ch = ((par * 4 + gg) ^ (x & 7)) * 8;   // c&7 == x&7
      s16x8 vh_ = *reinterpret_cast<const s16x8*>(&sV[0][rb + ch]);
      s16x8 vl_ = *reinterpret_cast<const s16x8*>(&sV[1][rb + ch]);
      Oacc[cs] = __builtin_amdgcn_mfma_f32_16x16x32_bf16(vh_, bh.v, Oacc[cs], 0, 0, 0);
      Oacc[cs] = __builtin_amdgcn_mfma_f32_16x16x32_bf16(vh_, bl.v, Oacc[cs], 0, 0, 0);
      Oacc[cs] = __builtin_amdgcn_mfma_f32_16x16x32_bf16(vl_, bh.v, Oacc[cs], 0, 0, 0);
    }
    __syncthreads();            // V consumed; K(t+1) drained

    if (mt + 1 < 64) {          // prefetch V(t+1), overlaps next QK^T
      const size_t vo = (size_t)(mt + 1) * 64;
      #pragma unroll
      for (int r = 0; r < 4; ++r) {
        gl2lds16(VhB + vo + vSrc[r], &sV[0][vDst[r]]);
        gl2lds16(VlB + vo + vSrc[r], &sV[1][vDst[r]]);
      }
    }
  }

  // ---- merge the two key-half flash states, divide by l, store ----
  const int q = g * 16 + x;
  if (gg == 0) { sMm[par][q] = m_run; sMl[par][q] = l_run; }
  __syncthreads();
  const float mo   = sMm[1 - par][q];
  const float lo   = sMl[1 - par][q];
  const float mtot = fmaxf(m_run, mo);
  const float w    = __expf(m_run - mtot);
  const float wo   = __expf(mo - mtot);
  const float lt   = l_run * w + lo * wo;
  const float sc   = w / lt;
  #pragma unroll
  for (int i = 0; i < 16; ++i) Oacc[i] *= sc;

  float* Obuf = reinterpret_cast<float*>(&sK[0][0]);   // 64 KB: [4][256][16]
  if (par == 1) {
    #pragma unroll
    for (int cs = 0; cs < 16; ++cs)
      #pragma unroll
      for (int r = 0; r < 4; ++r)
        Obuf[((g * 256) + cs * 16 + gg * 4 + r) * 16 + x] = Oacc[cs][r];
  }
  __syncthreads();
  if (par == 0) {
    #pragma unroll
    for (int cs = 0; cs < 16; ++cs)
      #pragma unroll
      for (int r = 0; r < 4; ++r) {
        float val = Oacc[cs][r] + Obuf[((g * 256) + cs * 16 + gg * 4 + r) * 16 + x];
        av[((size_t)b * CCH + cs * 16 + gg * 4 + r) * NPIX + qb + q] = val;
      }
  }
}

// ---------------------------------------------------------------------------
extern "C" void kernel_launch(void* const* d_in, const int* in_sizes, int n_in,
                              void* d_out, int out_size, void* d_ws, size_t ws_size,
                              hipStream_t stream) {
  const float* x_q  = (const float*)d_in[0];
  const float* x_kv = (const float*)d_in[1];
  const float* Wq = (const float*)d_in[2];
  const float* bq = (const float*)d_in[3];
  const float* Wk = (const float*)d_in[4];
  const float* bk = (const float*)d_in[5];
  const float* Wv = (const float*)d_in[6];
  const float* bv = (const float*)d_in[7];
  const float* W1 = (const float*)d_in[8];
  const float* b1 = (const float*)d_in[9];
  const float* W2 = (const float*)d_in[10];
  const float* b2 = (const float*)d_in[11];
  float* out = (float*)d_out;

  const size_t TS = (size_t)NB * NPIX * CCH;   // elems per bf16 tensor
  u16* Qth = (u16*)d_ws;
  u16* Qtl = Qth + TS;
  u16* Kth = Qtl + TS;
  u16* Ktl = Kth + TS;
  u16* Vh  = Ktl + TS;
  u16* Vl  = Vh + TS;
  float* AV  = (float*)(Vl + TS);              // 16.78 MB fp32
  float* HID = (float*)d_ws;                   // overlays Qth/Qtl (dead by then)

  dim3 cgrid(NPIX / 64, CCH / 64, NB);
  conv1x1_k<2, false><<<cgrid, 256, 0, stream>>>(x_q,  Wq, bq, Qth, Qtl);
  conv1x1_k<2, false><<<cgrid, 256, 0, stream>>>(x_kv, Wk, bk, Kth, Ktl);
  conv1x1_k<1, false><<<cgrid, 256, 0, stream>>>(x_kv, Wv, bv, Vh, Vl);

  attn_mfma<<<dim3(NPIX / 64, NB), 512, 0, stream>>>(Qth, Qtl, Kth, Ktl, Vh, Vl, AV);

  conv1x1_k<0, true ><<<cgrid, 256, 0, stream>>>(AV,  W1, b1, HID, nullptr);
  conv1x1_k<0, false><<<cgrid, 256, 0, stream>>>(HID, W2, b2, out, nullptr);
}

// Round 4
// 398.069 us; speedup vs baseline: 4.3717x; 1.4241x over previous
//
#include <hip/hip_runtime.h>
#include <math.h>

#define CCH 256
#define NPIX 4096
#define NB 4
#define NTOT (NB * NPIX)   // 16384 flat rows (b*4096 + n)

typedef _Float16 f16;
typedef f16 f16x8 __attribute__((ext_vector_type(8)));
typedef __fp16 fp16x2 __attribute__((ext_vector_type(2)));
typedef float f32x4 __attribute__((ext_vector_type(4)));
typedef unsigned short u16;
typedef unsigned int u32;

__device__ __forceinline__ u16 f2h(float f) {
  union { f16 h; u16 u; } c; c.h = (f16)f; return c.u;
}
__device__ __forceinline__ void fsplit(float v, u16& h, u16& l) {
  union { f16 h; u16 u; } a, b;
  a.h = (f16)v;                    // RN
  b.h = (f16)(v - (float)a.h);     // residual
  h = a.u; l = b.u;
}
__device__ __forceinline__ u32 pkh(float a, float b) {
  union { fp16x2 v; u32 u; } c;
  c.v = __builtin_amdgcn_cvt_pkrtz(a, b);
  return c.u;
}
__device__ __forceinline__ u32 shflu(u32 v, int s) { return (u32)__shfl((int)v, s, 64); }
__device__ __forceinline__ f32x4 mm(f16x8 a, f16x8 b, f32x4 c) {
  return __builtin_amdgcn_mfma_f32_16x16x32_f16(a, b, c, 0, 0, 0);
}
__device__ __forceinline__ f16x8 ld8(const u16* p) {
  return *reinterpret_cast<const f16x8*>(p);
}

using gas_t = const __attribute__((address_space(1))) void*;
using las_t = __attribute__((address_space(3))) void*;
__device__ __forceinline__ void gl2lds16(const void* g, void* l) {
  __builtin_amdgcn_global_load_lds((gas_t)g, (las_t)l, 16, 0, 0);
}

// ---------------------------------------------------------------------------
// prep_w: split 5 fp32 [256][256] weight matrices into fp16 hi/lo planes.
// wp layout: [mat][h=0/l=1][65536]
// ---------------------------------------------------------------------------
__global__ __launch_bounds__(256) void prep_w(
    const float* w0, const float* w1, const float* w2, const float* w3,
    const float* w4, u16* wp)
{
  const float* srcs[5] = {w0, w1, w2, w3, w4};
  const int m = blockIdx.y;
  const float* s = srcs[m];
  u16* ph = wp + (size_t)m * 2 * 65536;
  u16* pl = ph + 65536;
  const int i = (blockIdx.x * 256 + threadIdx.x) * 4;
  float4 v = *reinterpret_cast<const float4*>(s + i);
  ushort4 hv, lv;
  fsplit(v.x, hv.x, lv.x); fsplit(v.y, hv.y, lv.y);
  fsplit(v.z, hv.z, lv.z); fsplit(v.w, hv.w, lv.w);
  *reinterpret_cast<ushort4*>(ph + i) = hv;
  *reinterpret_cast<ushort4*>(pl + i) = lv;
}

// ---------------------------------------------------------------------------
// transpose_split: x [b][c][n] f32 -> xT [b*n][c] fp16 hi/lo planes.
// grid (64 n-tiles, 4 c-tiles, 8 = b + 4*input), block 256.
// ---------------------------------------------------------------------------
__global__ __launch_bounds__(256) void transpose_split(
    const float* xq, const float* xkv,
    u16* xqTh, u16* xqTl, u16* xkvTh, u16* xkvTl)
{
  __shared__ float T[64][65];
  const int nb = blockIdx.x * 64, cb = blockIdx.y * 64;
  const int z = blockIdx.z, b = z & 3, inp = z >> 2;
  const float* src = (inp ? xkv : xq) + (size_t)b * CCH * NPIX;
  u16* dh = inp ? xkvTh : xqTh;
  u16* dl = inp ? xkvTl : xqTl;
  const int t = threadIdx.x;
  #pragma unroll
  for (int k = 0; k < 4; ++k) {
    int e = t + 256 * k;
    int c = e >> 4, n4 = e & 15;
    float4 v = *reinterpret_cast<const float4*>(&src[(size_t)(cb + c) * NPIX + nb + n4 * 4]);
    T[c][n4 * 4 + 0] = v.x; T[c][n4 * 4 + 1] = v.y;
    T[c][n4 * 4 + 2] = v.z; T[c][n4 * 4 + 3] = v.w;
  }
  __syncthreads();
  const int n = t >> 2, cq = t & 3, c0 = cq * 16;
  alignas(16) u16 hh[16], ll[16];
  #pragma unroll
  for (int j = 0; j < 16; ++j) fsplit(T[c0 + j][n], hh[j], ll[j]);
  size_t base = ((size_t)b * NPIX + nb + n) * CCH + cb + c0;
  *reinterpret_cast<uint4*>(&dh[base])     = *reinterpret_cast<uint4*>(hh);
  *reinterpret_cast<uint4*>(&dh[base + 8]) = *reinterpret_cast<uint4*>(hh + 8);
  *reinterpret_cast<uint4*>(&dl[base])     = *reinterpret_cast<uint4*>(ll);
  *reinterpret_cast<uint4*>(&dl[base + 8]) = *reinterpret_cast<uint4*>(ll + 8);
}

// ---------------------------------------------------------------------------
// conv_s0: out[n][o] = A[n][c] * W[o][c]^T + bias.  A streamed via LDS,
// W resident in registers (B-frags). Block 512 = 8 waves; tile 64n x 128o.
// PL = streamed planes (2: h/l 3-term; 1: single 2-term).
// OM 0: split h/l out planes.  OM 1: single plane + ReLU.
// ---------------------------------------------------------------------------
template<int PL, int OM>
__global__ __launch_bounds__(512) void conv_s0(
    const u16* __restrict__ Ah, const u16* __restrict__ Al,
    const u16* __restrict__ Wh, const u16* __restrict__ Wl,
    const float* __restrict__ bias, u16* __restrict__ Oh, u16* __restrict__ Ol)
{
  __shared__ alignas(16) u16 sA[PL * 64 * 256];
  const int nb = blockIdx.x * 64, ob = blockIdx.y * 128;
  const int tid = threadIdx.x, wid = tid >> 6, lane = tid & 63;
  const int gg = lane >> 4, x = lane & 15;
  const int wn = wid & 1, wo = wid >> 1;

  f16x8 bh[2][8], bl[2][8];
  #pragma unroll
  for (int os = 0; os < 2; ++os) {
    const int row = ob + wo * 32 + os * 16 + x;
    #pragma unroll
    for (int kc = 0; kc < 8; ++kc) {
      bh[os][kc] = ld8(&Wh[(size_t)row * 256 + kc * 32 + gg * 8]);
      bl[os][kc] = ld8(&Wl[(size_t)row * 256 + kc * 32 + gg * 8]);
    }
  }
  const u16* Ap[2] = {Ah, Al};
  #pragma unroll
  for (int p = 0; p < PL; ++p)
    #pragma unroll
    for (int r = 0; r < 4; ++r) {
      int e = tid + 512 * r;
      int row = e >> 5, ch = e & 31;
      gl2lds16(Ap[p] + (size_t)(nb + row) * 256 + ((ch ^ (row & 7)) * 8),
               &sA[p * 16384 + e * 8]);
    }
  __syncthreads();

  f32x4 acc[2][2] = {};
  #pragma unroll
  for (int ms = 0; ms < 2; ++ms) {
    const int row = wn * 32 + ms * 16 + x;
    #pragma unroll
    for (int kc = 0; kc < 8; ++kc) {
      const int off = row * 256 + ((kc * 4 + gg) ^ (x & 7)) * 8;
      f16x8 a0 = ld8(&sA[off]);
      #pragma unroll
      for (int os = 0; os < 2; ++os) {
        acc[ms][os] = mm(a0, bh[os][kc], acc[ms][os]);
        acc[ms][os] = mm(a0, bl[os][kc], acc[ms][os]);
      }
      if (PL == 2) {
        f16x8 a1 = ld8(&sA[16384 + off]);
        #pragma unroll
        for (int os = 0; os < 2; ++os)
          acc[ms][os] = mm(a1, bh[os][kc], acc[ms][os]);
      }
    }
  }
  #pragma unroll
  for (int os = 0; os < 2; ++os) {
    const float bo = bias[ob + wo * 32 + os * 16 + x];
    const size_t col = ob + wo * 32 + os * 16 + x;
    #pragma unroll
    for (int ms = 0; ms < 2; ++ms)
      #pragma unroll
      for (int j = 0; j < 4; ++j) {
        float val = acc[ms][os][j] + bo;
        size_t row = nb + wn * 32 + ms * 16 + gg * 4 + j;
        if (OM == 1) {
          Oh[row * 256 + col] = f2h(fmaxf(val, 0.f));
        } else {
          u16 h, l; fsplit(val, h, l);
          Oh[row * 256 + col] = h;
          Ol[row * 256 + col] = l;
        }
      }
  }
}

// ---------------------------------------------------------------------------
// conv_s1: out[o][n] = W[o][c] * B[n][c]^T + bias.  W resident (A-frags),
// B (xT rows) streamed via LDS. Block 512; tile 128o x 64n.
// PL = streamed planes. OM 0: single u16 plane out; OM 1: f32 out.
// ---------------------------------------------------------------------------
template<int PL, int OM>
__global__ __launch_bounds__(512) void conv_s1(
    const u16* __restrict__ Wh, const u16* __restrict__ Wl,
    const u16* __restrict__ Bh, const u16* __restrict__ Bl,
    const float* __restrict__ bias, void* __restrict__ Out)
{
  __shared__ alignas(16) u16 sB[PL * 64 * 256];
  const int nb = blockIdx.x * 64, ob = blockIdx.y * 128;
  const int tid = threadIdx.x, wid = tid >> 6, lane = tid & 63;
  const int gg = lane >> 4, x = lane & 15;
  const int wn = wid & 1, wo = wid >> 1;

  f16x8 ah[2][8], al[2][8];
  #pragma unroll
  for (int as = 0; as < 2; ++as) {
    const int row = ob + wo * 32 + as * 16 + x;
    #pragma unroll
    for (int kc = 0; kc < 8; ++kc) {
      ah[as][kc] = ld8(&Wh[(size_t)row * 256 + kc * 32 + gg * 8]);
      al[as][kc] = ld8(&Wl[(size_t)row * 256 + kc * 32 + gg * 8]);
    }
  }
  const u16* Bp[2] = {Bh, Bl};
  #pragma unroll
  for (int p = 0; p < PL; ++p)
    #pragma unroll
    for (int r = 0; r < 4; ++r) {
      int e = tid + 512 * r;
      int row = e >> 5, ch = e & 31;
      gl2lds16(Bp[p] + (size_t)(nb + row) * 256 + ((ch ^ (row & 7)) * 8),
               &sB[p * 16384 + e * 8]);
    }
  __syncthreads();

  f32x4 acc[2][2] = {};
  #pragma unroll
  for (int ns = 0; ns < 2; ++ns) {
    const int row = wn * 32 + ns * 16 + x;
    #pragma unroll
    for (int kc = 0; kc < 8; ++kc) {
      const int off = row * 256 + ((kc * 4 + gg) ^ (x & 7)) * 8;
      f16x8 b0 = ld8(&sB[off]);
      #pragma unroll
      for (int as = 0; as < 2; ++as) {
        acc[as][ns] = mm(ah[as][kc], b0, acc[as][ns]);
        acc[as][ns] = mm(al[as][kc], b0, acc[as][ns]);
      }
      if (PL == 2) {
        f16x8 b1 = ld8(&sB[16384 + off]);
        #pragma unroll
        for (int as = 0; as < 2; ++as)
          acc[as][ns] = mm(ah[as][kc], b1, acc[as][ns]);
      }
    }
  }
  #pragma unroll
  for (int as = 0; as < 2; ++as)
    #pragma unroll
    for (int j = 0; j < 4; ++j) {
      const int o = ob + wo * 32 + as * 16 + gg * 4 + j;
      const float bo = bias[o];
      #pragma unroll
      for (int ns = 0; ns < 2; ++ns) {
        int nf = nb + wn * 32 + ns * 16 + x;
        float val = acc[as][ns][j] + bo;
        int b_ = nf >> 12, n_ = nf & 4095;
        size_t addr = ((size_t)b_ * 256 + o) * 4096 + n_;
        if (OM == 1) ((float*)Out)[addr] = val;
        else         ((u16*)Out)[addr] = f2h(val);
      }
    }
}

// ---------------------------------------------------------------------------
// MFMA flash attention, fp16. QK^T 3-term (2^-22), PV single-term (2^-11 on
// P,V — within budget). 8 waves = 4 q-groups x 2 key-halves. Defer-max.
// Writes AVt [b*n][c] single fp16 via LDS-transpose epilogue.
// ---------------------------------------------------------------------------
__global__ __launch_bounds__(512) void attn_mfma(
    const u16* __restrict__ Qh, const u16* __restrict__ Ql,
    const u16* __restrict__ Kh, const u16* __restrict__ Kl,
    const u16* __restrict__ Vs, u16* __restrict__ AVt)
{
  __shared__ alignas(16) u16 smem[49152];   // 96 KB: sKh|sKl|sV, reused as Obuf
  __shared__ float sMm[2][64], sMl[2][64];
  u16* sKh = smem;
  u16* sKl = smem + 16384;
  u16* sV  = smem + 32768;

  const int b = blockIdx.y, qb = blockIdx.x * 64;
  const int tid = threadIdx.x, wid = tid >> 6;
  const int g = wid & 3, par = wid >> 2;
  const int lane = tid & 63, gg = lane >> 4, x = lane & 15;

  f16x8 qh[8], ql[8];
  {
    const u16* qhp = Qh + ((size_t)b * NPIX + qb + g * 16 + x) * CCH;
    const u16* qlp = Ql + ((size_t)b * NPIX + qb + g * 16 + x) * CCH;
    #pragma unroll
    for (int kc = 0; kc < 8; ++kc) {
      qh[kc] = ld8(qhp + kc * 32 + gg * 8);
      ql[kc] = ld8(qlp + kc * 32 + gg * 8);
    }
  }
  int kSrc[4], kDst[4], vSrc[4], vDst[4];
  #pragma unroll
  for (int r = 0; r < 4; ++r) {
    int e = tid + 512 * r;
    int m = e >> 5, ch = e & 31;
    kSrc[r] = m * CCH + ((ch ^ (m & 7)) * 8);
    kDst[r] = e * 8;
    int c = e >> 3, c2 = e & 7;
    vSrc[r] = c * NPIX + ((c2 ^ (c & 7)) * 8);
    vDst[r] = e * 8;
  }
  const u16* KhB = Kh + (size_t)b * NPIX * CCH;
  const u16* KlB = Kl + (size_t)b * NPIX * CCH;
  const u16* VB  = Vs + (size_t)b * CCH * NPIX;

  f32x4 Oacc[16];
  #pragma unroll
  for (int i = 0; i < 16; ++i) Oacc[i] = f32x4{0.f, 0.f, 0.f, 0.f};
  float m_run = -INFINITY, l_run = 0.f;

  #pragma unroll
  for (int r = 0; r < 4; ++r) {
    gl2lds16(KhB + kSrc[r], &sKh[kDst[r]]);
    gl2lds16(KlB + kSrc[r], &sKl[kDst[r]]);
    gl2lds16(VB + vSrc[r], &sV[vDst[r]]);
  }
  __syncthreads();

  for (int mt = 0; mt < 64; ++mt) {
    f32x4 St[2];
    St[0] = f32x4{0.f, 0.f, 0.f, 0.f};
    St[1] = f32x4{0.f, 0.f, 0.f, 0.f};
    #pragma unroll
    for (int msub = 0; msub < 2; ++msub) {
      const int rb = (par * 32 + msub * 16 + x) * CCH;
      #pragma unroll
      for (int kc = 0; kc < 8; ++kc) {
        const int off = rb + ((kc * 4 + gg) ^ (x & 7)) * 8;
        f16x8 ah_ = ld8(&sKh[off]);
        f16x8 al_ = ld8(&sKl[off]);
        St[msub] = mm(ah_, qh[kc], St[msub]);
        St[msub] = mm(ah_, ql[kc], St[msub]);
        St[msub] = mm(al_, qh[kc], St[msub]);
      }
    }
    __syncthreads();            // K consumed; V(t) drained

    if (mt + 1 < 64) {
      const size_t ko = (size_t)(mt + 1) * 64 * CCH;
      #pragma unroll
      for (int r = 0; r < 4; ++r) {
        gl2lds16(KhB + ko + kSrc[r], &sKh[kDst[r]]);
        gl2lds16(KlB + ko + kSrc[r], &sKl[kDst[r]]);
      }
    }

    // ---- online softmax with defer-max (THR=8) ----
    float vmax = fmaxf(fmaxf(fmaxf(St[0][0], St[0][1]), fmaxf(St[0][2], St[0][3])),
                       fmaxf(fmaxf(St[1][0], St[1][1]), fmaxf(St[1][2], St[1][3])));
    vmax = fmaxf(vmax, __shfl_xor(vmax, 16, 64));
    vmax = fmaxf(vmax, __shfl_xor(vmax, 32, 64));
    float alpha = 1.f;
    if (!__all(vmax <= m_run + 8.f)) {
      const float mnew = fmaxf(m_run, vmax);
      alpha = __expf(m_run - mnew);
      m_run = mnew;
      #pragma unroll
      for (int i = 0; i < 16; ++i) Oacc[i] *= alpha;
    }
    float p[2][4], ps = 0.f;
    #pragma unroll
    for (int msx = 0; msx < 2; ++msx)
      #pragma unroll
      for (int r = 0; r < 4; ++r) {
        p[msx][r] = __expf(St[msx][r] - m_run);
        ps += p[msx][r];
      }
    ps += __shfl_xor(ps, 16, 64);
    ps += __shfl_xor(ps, 32, 64);
    l_run = l_run * alpha + ps;

    // ---- pack P fp16 and route to PV B-frag via 8 shfls ----
    u32 Pp[2][2];
    #pragma unroll
    for (int msx = 0; msx < 2; ++msx) {
      Pp[msx][0] = pkh(p[msx][0], p[msx][1]);
      Pp[msx][1] = pkh(p[msx][2], p[msx][3]);
    }
    const int src0 = ((gg & 1) * 2) * 16 + x, src1 = src0 + 16;
    const bool sel = (gg >> 1) != 0;
    union { u32 u[4]; f16x8 v; } pb;
    {
      u32 a0 = shflu(Pp[0][0], src0), a1 = shflu(Pp[1][0], src0);
      u32 b0 = shflu(Pp[0][1], src0), b1 = shflu(Pp[1][1], src0);
      u32 c0 = shflu(Pp[0][0], src1), c1 = shflu(Pp[1][0], src1);
      u32 d0 = shflu(Pp[0][1], src1), d1 = shflu(Pp[1][1], src1);
      pb.u[0] = sel ? a1 : a0;
      pb.u[1] = sel ? b1 : b0;
      pb.u[2] = sel ? c1 : c0;
      pb.u[3] = sel ? d1 : d0;
    }

    // ---- PV: single MFMA per channel-slice ----
    #pragma unroll
    for (int cs = 0; cs < 16; ++cs) {
      const int off = (cs * 16 + x) * 64 + ((par * 4 + gg) ^ (x & 7)) * 8;
      Oacc[cs] = mm(ld8(&sV[off]), pb.v, Oacc[cs]);
    }
    __syncthreads();            // V consumed; K(t+1) drained

    if (mt + 1 < 64) {
      const size_t vo = (size_t)(mt + 1) * 64;
      #pragma unroll
      for (int r = 0; r < 4; ++r)
        gl2lds16(VB + vo + vSrc[r], &sV[vDst[r]]);
    }
  }

  // ---- merge key-halves, normalize, transpose, store AVt [n][c] fp16 ----
  const int q = g * 16 + x;
  if (gg == 0) { sMm[par][q] = m_run; sMl[par][q] = l_run; }
  __syncthreads();
  const float mo = sMm[1 - par][q], lo = sMl[1 - par][q];
  const float mtot = fmaxf(m_run, mo);
  const float w = __expf(m_run - mtot), wo_ = __expf(mo - mtot);
  const float lt = l_run * w + lo * wo_;
  const float sc = w / lt;
  #pragma unroll
  for (int i = 0; i < 16; ++i) Oacc[i] *= sc;

  float* Obuf = reinterpret_cast<float*>(smem);
  #define OFF_(G, C, X) ((G) * 4360 + (C) * 17 + (X))
  if (par == 1) {
    #pragma unroll
    for (int cs = 0; cs < 16; ++cs)
      #pragma unroll
      for (int r = 0; r < 4; ++r)
        Obuf[OFF_(g, cs * 16 + gg * 4 + r, x)] = Oacc[cs][r];
  }
  __syncthreads();
  if (par == 0) {
    #pragma unroll
    for (int cs = 0; cs < 16; ++cs)
      #pragma unroll
      for (int r = 0; r < 4; ++r)
        Obuf[OFF_(g, cs * 16 + gg * 4 + r, x)] += Oacc[cs][r];
  }
  __syncthreads();
  const int n_loc = tid & 63, cq = tid >> 6;
  const int g2 = n_loc >> 4, x2 = n_loc & 15, c0 = cq * 32;
  alignas(16) u32 wds[16];
  #pragma unroll
  for (int j = 0; j < 16; ++j)
    wds[j] = pkh(Obuf[OFF_(g2, c0 + 2 * j, x2)], Obuf[OFF_(g2, c0 + 2 * j + 1, x2)]);
  u16* dst = AVt + ((size_t)b * NPIX + qb + n_loc) * CCH + c0;
  #pragma unroll
  for (int k = 0; k < 4; ++k)
    *reinterpret_cast<uint4*>(dst + k * 8) = *reinterpret_cast<uint4*>(&wds[k * 4]);
}

// ---------------------------------------------------------------------------
extern "C" void kernel_launch(void* const* d_in, const int* in_sizes, int n_in,
                              void* d_out, int out_size, void* d_ws, size_t ws_size,
                              hipStream_t stream) {
  const float* x_q  = (const float*)d_in[0];
  const float* x_kv = (const float*)d_in[1];
  const float* Wq = (const float*)d_in[2];
  const float* bq = (const float*)d_in[3];
  const float* Wk = (const float*)d_in[4];
  const float* bk = (const float*)d_in[5];
  const float* Wv = (const float*)d_in[6];
  const float* bv = (const float*)d_in[7];
  const float* W1 = (const float*)d_in[8];
  const float* b1 = (const float*)d_in[9];
  const float* W2 = (const float*)d_in[10];
  const float* b2 = (const float*)d_in[11];
  float* out = (float*)d_out;

  u16* ws = (u16*)d_ws;
  const size_t P = (size_t)NTOT * CCH;   // 4,194,304
  u16* xqTh  = ws;
  u16* xqTl  = ws + P;
  u16* xkvTh = ws + 2 * P;
  u16* xkvTl = ws + 3 * P;
  u16* Wp    = ws + 4 * P;               // 10 planes x 65536
  u16* Whq = Wp + 0 * 65536, *Wlq = Wp + 1 * 65536;
  u16* Whk = Wp + 2 * 65536, *Wlk = Wp + 3 * 65536;
  u16* Whv = Wp + 4 * 65536, *Wlv = Wp + 5 * 65536;
  u16* Wh1 = Wp + 6 * 65536, *Wl1 = Wp + 7 * 65536;
  u16* Wh2 = Wp + 8 * 65536, *Wl2 = Wp + 9 * 65536;
  u16* base2 = Wp + 10 * 65536;
  u16* Qhp = base2 + 0 * P;
  u16* Qlp = base2 + 1 * P;
  u16* Khp = base2 + 2 * P;
  u16* Klp = base2 + 3 * P;
  u16* Vhp = base2 + 4 * P;
  u16* AVt  = xqTh;    // xqT dead after conv-Q
  u16* HIDt = xqTl;

  prep_w<<<dim3(64, 5), 256, 0, stream>>>(Wq, Wk, Wv, W1, W2, Wp);
  transpose_split<<<dim3(64, 4, 8), 256, 0, stream>>>(
      x_q, x_kv, xqTh, xqTl, xkvTh, xkvTl);

  conv_s0<2, 0><<<dim3(256, 2), 512, 0, stream>>>(xqTh, xqTl, Whq, Wlq, bq, Qhp, Qlp);
  conv_s0<2, 0><<<dim3(256, 2), 512, 0, stream>>>(xkvTh, xkvTl, Whk, Wlk, bk, Khp, Klp);
  conv_s1<2, 0><<<dim3(256, 2), 512, 0, stream>>>(Whv, Wlv, xkvTh, xkvTl, bv, (void*)Vhp);

  attn_mfma<<<dim3(NPIX / 64, NB), 512, 0, stream>>>(Qhp, Qlp, Khp, Klp, Vhp, AVt);

  conv_s0<1, 1><<<dim3(256, 2), 512, 0, stream>>>(AVt, nullptr, Wh1, Wl1, b1, HIDt, nullptr);
  conv_s1<1, 1><<<dim3(256, 2), 512, 0, stream>>>(Wh2, Wl2, HIDt, nullptr, b2, (void*)out);
}

// Round 5
// 389.591 us; speedup vs baseline: 4.4668x; 1.0218x over previous
//
#include <hip/hip_runtime.h>
#include <math.h>

#define CCH 256
#define NPIX 4096
#define NB 4
#define NTOT (NB * NPIX)   // 16384 flat rows (b*4096 + n)

typedef _Float16 f16;
typedef f16 f16x8 __attribute__((ext_vector_type(8)));
typedef __fp16 fp16x2 __attribute__((ext_vector_type(2)));
typedef float f32x4 __attribute__((ext_vector_type(4)));
typedef unsigned short u16;
typedef unsigned int u32;

__device__ __forceinline__ u16 f2h(float f) {
  union { f16 h; u16 u; } c; c.h = (f16)f; return c.u;
}
__device__ __forceinline__ void fsplit(float v, u16& h, u16& l) {
  union { f16 h; u16 u; } a, b;
  a.h = (f16)v;                    // RN
  b.h = (f16)(v - (float)a.h);     // residual
  h = a.u; l = b.u;
}
__device__ __forceinline__ u32 pkh(float a, float b) {
  union { fp16x2 v; u32 u; } c;
  c.v = __builtin_amdgcn_cvt_pkrtz(a, b);
  return c.u;
}
__device__ __forceinline__ u32 shflu(u32 v, int s) { return (u32)__shfl((int)v, s, 64); }
__device__ __forceinline__ f32x4 mm(f16x8 a, f16x8 b, f32x4 c) {
  return __builtin_amdgcn_mfma_f32_16x16x32_f16(a, b, c, 0, 0, 0);
}
__device__ __forceinline__ f16x8 ld8(const u16* p) {
  return *reinterpret_cast<const f16x8*>(p);
}

// ---- LDS bank swizzles (stage source permuted; read applies same map) ----
// 32-slot rows (256 u16 = 512 B): 2-way max (free).
__device__ __forceinline__ int swz_rd(int c, int x) {   // x = lane&15 = row&15
  return c ^ x ^ ((c & 3) << 3);
}
__device__ __forceinline__ int swz_st(int s, int r) {
  return s ^ (r & 15) ^ (((s ^ r) & 3) << 3);
}
// 16-slot rows (V [c][128] u16 = 256 B): 4-way max.
__device__ __forceinline__ int swzv_rd(int c, int x) {
  return c ^ x ^ ((c & 3) << 2);
}
__device__ __forceinline__ int swzv_st(int s, int r) {
  return s ^ (r & 15) ^ (((s ^ r) & 3) << 2);
}

using gas_t = const __attribute__((address_space(1))) void*;
using las_t = __attribute__((address_space(3))) void*;
__device__ __forceinline__ void gl2lds16(const void* g, void* l) {
  __builtin_amdgcn_global_load_lds((gas_t)g, (las_t)l, 16, 0, 0);
}

// ---------------------------------------------------------------------------
// prep_w: split 5 fp32 [256][256] weight matrices into fp16 hi/lo planes.
// ---------------------------------------------------------------------------
__global__ __launch_bounds__(256) void prep_w(
    const float* w0, const float* w1, const float* w2, const float* w3,
    const float* w4, u16* wp)
{
  const float* srcs[5] = {w0, w1, w2, w3, w4};
  const int m = blockIdx.y;
  const float* s = srcs[m];
  u16* ph = wp + (size_t)m * 2 * 65536;
  u16* pl = ph + 65536;
  const int i = (blockIdx.x * 256 + threadIdx.x) * 4;
  float4 v = *reinterpret_cast<const float4*>(s + i);
  ushort4 hv, lv;
  fsplit(v.x, hv.x, lv.x); fsplit(v.y, hv.y, lv.y);
  fsplit(v.z, hv.z, lv.z); fsplit(v.w, hv.w, lv.w);
  *reinterpret_cast<ushort4*>(ph + i) = hv;
  *reinterpret_cast<ushort4*>(pl + i) = lv;
}

// ---------------------------------------------------------------------------
// transpose_split: x [b][c][n] f32 -> xT [b*n][c] fp16 hi/lo planes.
// ---------------------------------------------------------------------------
__global__ __launch_bounds__(256) void transpose_split(
    const float* xq, const float* xkv,
    u16* xqTh, u16* xqTl, u16* xkvTh, u16* xkvTl)
{
  __shared__ float T[64][65];
  const int nb = blockIdx.x * 64, cb = blockIdx.y * 64;
  const int z = blockIdx.z, b = z & 3, inp = z >> 2;
  const float* src = (inp ? xkv : xq) + (size_t)b * CCH * NPIX;
  u16* dh = inp ? xkvTh : xqTh;
  u16* dl = inp ? xkvTl : xqTl;
  const int t = threadIdx.x;
  #pragma unroll
  for (int k = 0; k < 4; ++k) {
    int e = t + 256 * k;
    int c = e >> 4, n4 = e & 15;
    float4 v = *reinterpret_cast<const float4*>(&src[(size_t)(cb + c) * NPIX + nb + n4 * 4]);
    T[c][n4 * 4 + 0] = v.x; T[c][n4 * 4 + 1] = v.y;
    T[c][n4 * 4 + 2] = v.z; T[c][n4 * 4 + 3] = v.w;
  }
  __syncthreads();
  const int n = t >> 2, cq = t & 3, c0 = cq * 16;
  alignas(16) u16 hh[16], ll[16];
  #pragma unroll
  for (int j = 0; j < 16; ++j) fsplit(T[c0 + j][n], hh[j], ll[j]);
  size_t base = ((size_t)b * NPIX + nb + n) * CCH + cb + c0;
  *reinterpret_cast<uint4*>(&dh[base])     = *reinterpret_cast<uint4*>(hh);
  *reinterpret_cast<uint4*>(&dh[base + 8]) = *reinterpret_cast<uint4*>(hh + 8);
  *reinterpret_cast<uint4*>(&dl[base])     = *reinterpret_cast<uint4*>(ll);
  *reinterpret_cast<uint4*>(&dl[base + 8]) = *reinterpret_cast<uint4*>(ll + 8);
}

// ---------------------------------------------------------------------------
// conv_s0: out[n][o] = A[n][c] * W[o][c]^T + bias.  A streamed via LDS,
// W resident (B-frags). Block 512 = 8 waves; tile 64n x 128o.
// ---------------------------------------------------------------------------
template<int PL, int OM>
__global__ __launch_bounds__(512) void conv_s0(
    const u16* __restrict__ Ah, const u16* __restrict__ Al,
    const u16* __restrict__ Wh, const u16* __restrict__ Wl,
    const float* __restrict__ bias, u16* __restrict__ Oh, u16* __restrict__ Ol)
{
  __shared__ alignas(16) u16 sA[PL * 64 * 256];
  const int nb = blockIdx.x * 64, ob = blockIdx.y * 128;
  const int tid = threadIdx.x, wid = tid >> 6, lane = tid & 63;
  const int gg = lane >> 4, x = lane & 15;
  const int wn = wid & 1, wo = wid >> 1;

  f16x8 bh[2][8], bl[2][8];
  #pragma unroll
  for (int os = 0; os < 2; ++os) {
    const int row = ob + wo * 32 + os * 16 + x;
    #pragma unroll
    for (int kc = 0; kc < 8; ++kc) {
      bh[os][kc] = ld8(&Wh[(size_t)row * 256 + kc * 32 + gg * 8]);
      bl[os][kc] = ld8(&Wl[(size_t)row * 256 + kc * 32 + gg * 8]);
    }
  }
  const u16* Ap[2] = {Ah, Al};
  #pragma unroll
  for (int p = 0; p < PL; ++p)
    #pragma unroll
    for (int r = 0; r < 4; ++r) {
      int e = tid + 512 * r;
      int row = e >> 5, s = e & 31;
      int c = swz_st(s, row);
      gl2lds16(Ap[p] + (size_t)(nb + row) * 256 + c * 8, &sA[p * 16384 + e * 8]);
    }
  __syncthreads();

  f32x4 acc[2][2] = {};
  #pragma unroll
  for (int ms = 0; ms < 2; ++ms) {
    const int row = wn * 32 + ms * 16 + x;
    #pragma unroll
    for (int kc = 0; kc < 8; ++kc) {
      const int off = row * 256 + swz_rd(kc * 4 + gg, x) * 8;
      f16x8 a0 = ld8(&sA[off]);
      #pragma unroll
      for (int os = 0; os < 2; ++os) {
        acc[ms][os] = mm(a0, bh[os][kc], acc[ms][os]);
        acc[ms][os] = mm(a0, bl[os][kc], acc[ms][os]);
      }
      if (PL == 2) {
        f16x8 a1 = ld8(&sA[16384 + off]);
        #pragma unroll
        for (int os = 0; os < 2; ++os)
          acc[ms][os] = mm(a1, bh[os][kc], acc[ms][os]);
      }
    }
  }
  #pragma unroll
  for (int os = 0; os < 2; ++os) {
    const float bo = bias[ob + wo * 32 + os * 16 + x];
    const size_t col = ob + wo * 32 + os * 16 + x;
    #pragma unroll
    for (int ms = 0; ms < 2; ++ms)
      #pragma unroll
      for (int j = 0; j < 4; ++j) {
        float val = acc[ms][os][j] + bo;
        size_t row = nb + wn * 32 + ms * 16 + gg * 4 + j;
        if (OM == 1) {
          Oh[row * 256 + col] = f2h(fmaxf(val, 0.f));
        } else {
          u16 h, l; fsplit(val, h, l);
          Oh[row * 256 + col] = h;
          Ol[row * 256 + col] = l;
        }
      }
  }
}

// ---------------------------------------------------------------------------
// conv_s1: out[o][n] = W[o][c] * B[n][c]^T + bias.  W resident (A-frags),
// B streamed via LDS. Block 512; tile 128o x 64n.
// ---------------------------------------------------------------------------
template<int PL, int OM>
__global__ __launch_bounds__(512) void conv_s1(
    const u16* __restrict__ Wh, const u16* __restrict__ Wl,
    const u16* __restrict__ Bh, const u16* __restrict__ Bl,
    const float* __restrict__ bias, void* __restrict__ Out)
{
  __shared__ alignas(16) u16 sB[PL * 64 * 256];
  const int nb = blockIdx.x * 64, ob = blockIdx.y * 128;
  const int tid = threadIdx.x, wid = tid >> 6, lane = tid & 63;
  const int gg = lane >> 4, x = lane & 15;
  const int wn = wid & 1, wo = wid >> 1;

  f16x8 ah[2][8], al[2][8];
  #pragma unroll
  for (int as = 0; as < 2; ++as) {
    const int row = ob + wo * 32 + as * 16 + x;
    #pragma unroll
    for (int kc = 0; kc < 8; ++kc) {
      ah[as][kc] = ld8(&Wh[(size_t)row * 256 + kc * 32 + gg * 8]);
      al[as][kc] = ld8(&Wl[(size_t)row * 256 + kc * 32 + gg * 8]);
    }
  }
  const u16* Bp[2] = {Bh, Bl};
  #pragma unroll
  for (int p = 0; p < PL; ++p)
    #pragma unroll
    for (int r = 0; r < 4; ++r) {
      int e = tid + 512 * r;
      int row = e >> 5, s = e & 31;
      int c = swz_st(s, row);
      gl2lds16(Bp[p] + (size_t)(nb + row) * 256 + c * 8, &sB[p * 16384 + e * 8]);
    }
  __syncthreads();

  f32x4 acc[2][2] = {};
  #pragma unroll
  for (int ns = 0; ns < 2; ++ns) {
    const int row = wn * 32 + ns * 16 + x;
    #pragma unroll
    for (int kc = 0; kc < 8; ++kc) {
      const int off = row * 256 + swz_rd(kc * 4 + gg, x) * 8;
      f16x8 b0 = ld8(&sB[off]);
      #pragma unroll
      for (int as = 0; as < 2; ++as) {
        acc[as][ns] = mm(ah[as][kc], b0, acc[as][ns]);
        acc[as][ns] = mm(al[as][kc], b0, acc[as][ns]);
      }
      if (PL == 2) {
        f16x8 b1 = ld8(&sB[16384 + off]);
        #pragma unroll
        for (int as = 0; as < 2; ++as)
          acc[as][ns] = mm(ah[as][kc], b1, acc[as][ns]);
      }
    }
  }
  #pragma unroll
  for (int as = 0; as < 2; ++as)
    #pragma unroll
    for (int j = 0; j < 4; ++j) {
      const int o = ob + wo * 32 + as * 16 + gg * 4 + j;
      const float bo = bias[o];
      #pragma unroll
      for (int ns = 0; ns < 2; ++ns) {
        int nf = nb + wn * 32 + ns * 16 + x;
        float val = acc[as][ns][j] + bo;
        int b_ = nf >> 12, n_ = nf & 4095;
        size_t addr = ((size_t)b_ * 256 + o) * 4096 + n_;
        if (OM == 1) ((float*)Out)[addr] = val;
        else         ((u16*)Out)[addr] = f2h(val);
      }
    }
}

// ---------------------------------------------------------------------------
// conv_kv: fused K and V convs — ONE xkvT LDS stage serves K (A-operand) and
// V (B-operand). Block 512 = 8 waves: waves 0-3 K-part, 4-7 V-part.
// K: out[n][o] h/l planes.  V: out[o][n] single fp16 plane.
// ---------------------------------------------------------------------------
__global__ __launch_bounds__(512) void conv_kv(
    const u16* __restrict__ xh, const u16* __restrict__ xl,
    const u16* __restrict__ Wkh, const u16* __restrict__ Wkl,
    const u16* __restrict__ Wvh, const u16* __restrict__ Wvl,
    const float* __restrict__ bk, const float* __restrict__ bv,
    u16* __restrict__ Kh, u16* __restrict__ Kl, u16* __restrict__ Vh)
{
  __shared__ alignas(16) u16 sA[2 * 64 * 256];   // 64 KB h|l
  const int nb = blockIdx.x * 64, ob = blockIdx.y * 128;
  const int tid = threadIdx.x, wid = tid >> 6, lane = tid & 63;
  const int gg = lane >> 4, x = lane & 15;
  const int part = wid >> 2;     // 0 = K, 1 = V
  const int wo = wid & 3;        // 32-o slice of the 128-o half

  const u16* Wh = part ? Wvh : Wkh;
  const u16* Wl = part ? Wvl : Wkl;
  f16x8 wh[2][8], wl[2][8];
  #pragma unroll
  for (int os = 0; os < 2; ++os) {
    const int row = ob + wo * 32 + os * 16 + x;
    #pragma unroll
    for (int kc = 0; kc < 8; ++kc) {
      wh[os][kc] = ld8(&Wh[(size_t)row * 256 + kc * 32 + gg * 8]);
      wl[os][kc] = ld8(&Wl[(size_t)row * 256 + kc * 32 + gg * 8]);
    }
  }
  const u16* Ap[2] = {xh, xl};
  #pragma unroll
  for (int p = 0; p < 2; ++p)
    #pragma unroll
    for (int r = 0; r < 4; ++r) {
      int e = tid + 512 * r;
      int row = e >> 5, s = e & 31;
      int c = swz_st(s, row);
      gl2lds16(Ap[p] + (size_t)(nb + row) * 256 + c * 8, &sA[p * 16384 + e * 8]);
    }
  __syncthreads();

  f32x4 acc[4][2] = {};   // [n-slice][os]
  #pragma unroll
  for (int ns = 0; ns < 4; ++ns) {
    const int row = ns * 16 + x;
    #pragma unroll
    for (int kc = 0; kc < 8; ++kc) {
      const int off = row * 256 + swz_rd(kc * 4 + gg, x) * 8;
      f16x8 a0 = ld8(&sA[off]);
      f16x8 a1 = ld8(&sA[16384 + off]);
      if (part == 0) {
        #pragma unroll
        for (int os = 0; os < 2; ++os) {
          acc[ns][os] = mm(a0, wh[os][kc], acc[ns][os]);
          acc[ns][os] = mm(a0, wl[os][kc], acc[ns][os]);
          acc[ns][os] = mm(a1, wh[os][kc], acc[ns][os]);
        }
      } else {
        #pragma unroll
        for (int os = 0; os < 2; ++os) {
          acc[ns][os] = mm(wh[os][kc], a0, acc[ns][os]);
          acc[ns][os] = mm(wl[os][kc], a0, acc[ns][os]);
          acc[ns][os] = mm(wh[os][kc], a1, acc[ns][os]);
        }
      }
    }
  }

  if (part == 0) {
    #pragma unroll
    for (int os = 0; os < 2; ++os) {
      const int o = ob + wo * 32 + os * 16 + x;
      const float bo = bk[o];
      #pragma unroll
      for (int ns = 0; ns < 4; ++ns)
        #pragma unroll
        for (int j = 0; j < 4; ++j) {
          float val = acc[ns][os][j] + bo;
          u16 h, l; fsplit(val, h, l);
          size_t row = nb + ns * 16 + gg * 4 + j;
          Kh[row * 256 + o] = h;
          Kl[row * 256 + o] = l;
        }
    }
  } else {
    #pragma unroll
    for (int os = 0; os < 2; ++os)
      #pragma unroll
      for (int j = 0; j < 4; ++j) {
        const int o = ob + wo * 32 + os * 16 + gg * 4 + j;
        const float bo = bv[o];
        #pragma unroll
        for (int ns = 0; ns < 4; ++ns) {
          int nf = nb + ns * 16 + x;
          float val = acc[ns][os][j] + bo;
          int b_ = nf >> 12, n_ = nf & 4095;
          Vh[((size_t)b_ * 256 + o) * 4096 + n_] = f2h(val);
        }
      }
  }
}

// ---------------------------------------------------------------------------
// MFMA flash attention, fp16. QK^T 3-term, PV 1-term. 8 waves = 4 q-groups x
// 2 key-halves. Defer-max. New: 2-way K swizzle, V [c][128] pair-staged.
// ---------------------------------------------------------------------------
__global__ __launch_bounds__(512) void attn_mfma(
    const u16* __restrict__ Qh, const u16* __restrict__ Ql,
    const u16* __restrict__ Kh, const u16* __restrict__ Kl,
    const u16* __restrict__ Vs, u16* __restrict__ AVt)
{
  __shared__ alignas(16) u16 smem[65536];   // 128 KB: sKh|sKl|sV
  __shared__ float sMm[2][64], sMl[2][64];
  u16* sKh = smem;                 // [64][256]
  u16* sKl = smem + 16384;
  u16* sV  = smem + 32768;         // [256][128]

  const int b = blockIdx.y, qb = blockIdx.x * 64;
  const int tid = threadIdx.x, wid = tid >> 6;
  const int g = wid & 3, par = wid >> 2;
  const int lane = tid & 63, gg = lane >> 4, x = lane & 15;

  f16x8 qh[8], ql[8];
  {
    const u16* qhp = Qh + ((size_t)b * NPIX + qb + g * 16 + x) * CCH;
    const u16* qlp = Ql + ((size_t)b * NPIX + qb + g * 16 + x) * CCH;
    #pragma unroll
    for (int kc = 0; kc < 8; ++kc) {
      qh[kc] = ld8(qhp + kc * 32 + gg * 8);
      ql[kc] = ld8(qlp + kc * 32 + gg * 8);
    }
  }
  const u16* KhB = Kh + (size_t)b * NPIX * CCH;
  const u16* KlB = Kl + (size_t)b * NPIX * CCH;
  const u16* VB  = Vs + (size_t)b * CCH * NPIX;

#define STAGE_K(KO) do {                                        \
    _Pragma("unroll")                                           \
    for (int j_ = 0; j_ < 4; ++j_) {                            \
      int e_ = tid + 512 * j_;                                  \
      int r_ = e_ >> 5, s_ = e_ & 31;                           \
      int c_ = swz_st(s_, r_);                                  \
      size_t src_ = (KO) + (size_t)r_ * CCH + c_ * 8;           \
      gl2lds16(KhB + src_, &sKh[e_ * 8]);                       \
      gl2lds16(KlB + src_, &sKl[e_ * 8]);                       \
    } } while (0)

#define STAGE_V(KB) do {                                        \
    _Pragma("unroll")                                           \
    for (int j_ = 0; j_ < 8; ++j_) {                            \
      int e_ = tid + 512 * j_;                                  \
      int r_ = e_ >> 4, s_ = e_ & 15;                           \
      int c_ = swzv_st(s_, r_);                                 \
      gl2lds16(VB + (KB) + (size_t)r_ * NPIX + c_ * 8, &sV[e_ * 8]); \
    } } while (0)

  f32x4 Oacc[16];
  #pragma unroll
  for (int i = 0; i < 16; ++i) Oacc[i] = f32x4{0.f, 0.f, 0.f, 0.f};
  float m_run = -INFINITY, l_run = 0.f;

  STAGE_K((size_t)0);
  STAGE_V((size_t)0);
  __syncthreads();

  for (int mt = 0; mt < 64; ++mt) {
    f32x4 St[2];
    St[0] = f32x4{0.f, 0.f, 0.f, 0.f};
    St[1] = f32x4{0.f, 0.f, 0.f, 0.f};
    #pragma unroll
    for (int msub = 0; msub < 2; ++msub) {
      const int rb = (par * 32 + msub * 16 + x) * CCH;
      #pragma unroll
      for (int kc = 0; kc < 8; ++kc) {
        const int off = rb + swz_rd(kc * 4 + gg, x) * 8;
        f16x8 ah_ = ld8(&sKh[off]);
        f16x8 al_ = ld8(&sKl[off]);
        St[msub] = mm(ah_, qh[kc], St[msub]);
        St[msub] = mm(ah_, ql[kc], St[msub]);
        St[msub] = mm(al_, qh[kc], St[msub]);
      }
    }
    __syncthreads();            // K consumed; V-pair stage drained

    if (mt + 1 < 64) STAGE_K((size_t)(mt + 1) * 64 * CCH);

    // ---- online softmax with defer-max (THR=8) ----
    float vmax = fmaxf(fmaxf(fmaxf(St[0][0], St[0][1]), fmaxf(St[0][2], St[0][3])),
                       fmaxf(fmaxf(St[1][0], St[1][1]), fmaxf(St[1][2], St[1][3])));
    vmax = fmaxf(vmax, __shfl_xor(vmax, 16, 64));
    vmax = fmaxf(vmax, __shfl_xor(vmax, 32, 64));
    float alpha = 1.f;
    if (!__all(vmax <= m_run + 8.f)) {
      const float mnew = fmaxf(m_run, vmax);
      alpha = __expf(m_run - mnew);
      m_run = mnew;
      #pragma unroll
      for (int i = 0; i < 16; ++i) Oacc[i] *= alpha;
    }
    float p[2][4], ps = 0.f;
    #pragma unroll
    for (int msx = 0; msx < 2; ++msx)
      #pragma unroll
      for (int r = 0; r < 4; ++r) {
        p[msx][r] = __expf(St[msx][r] - m_run);
        ps += p[msx][r];
      }
    ps += __shfl_xor(ps, 16, 64);
    ps += __shfl_xor(ps, 32, 64);
    l_run = l_run * alpha + ps;

    // ---- pack P fp16 and route to PV B-frag via 8 shfls ----
    u32 Pp[2][2];
    #pragma unroll
    for (int msx = 0; msx < 2; ++msx) {
      Pp[msx][0] = pkh(p[msx][0], p[msx][1]);
      Pp[msx][1] = pkh(p[msx][2], p[msx][3]);
    }
    const int src0 = ((gg & 1) * 2) * 16 + x, src1 = src0 + 16;
    const bool sel = (gg >> 1) != 0;
    union { u32 u[4]; f16x8 v; } pb;
    {
      u32 a0 = shflu(Pp[0][0], src0), a1 = shflu(Pp[1][0], src0);
      u32 b0 = shflu(Pp[0][1], src0), b1 = shflu(Pp[1][1], src0);
      u32 c0 = shflu(Pp[0][0], src1), c1 = shflu(Pp[1][0], src1);
      u32 d0 = shflu(Pp[0][1], src1), d1 = shflu(Pp[1][1], src1);
      pb.u[0] = sel ? a1 : a0;
      pb.u[1] = sel ? b1 : b0;
      pb.u[2] = sel ? c1 : c0;
      pb.u[3] = sel ? d1 : d0;
    }

    // ---- PV: single MFMA per channel-slice; V cols = (mt&1)*64 ----
    const int ct = ((mt & 1) << 3) + par * 4 + gg;
    const int sv = swzv_rd(ct, x);
    #pragma unroll
    for (int cs = 0; cs < 16; ++cs) {
      const int off = (cs * 16 + x) * 128 + sv * 8;
      Oacc[cs] = mm(ld8(&sV[off]), pb.v, Oacc[cs]);
    }
    __syncthreads();            // V consumed for this iter; K(t+1) drained

    if ((mt & 1) && mt + 1 < 64) STAGE_V((size_t)(mt + 1) * 64);
  }

  // ---- merge key-halves, normalize, transpose, store AVt [n][c] fp16 ----
  const int q = g * 16 + x;
  if (gg == 0) { sMm[par][q] = m_run; sMl[par][q] = l_run; }
  __syncthreads();
  const float mo = sMm[1 - par][q], lo = sMl[1 - par][q];
  const float mtot = fmaxf(m_run, mo);
  const float w = __expf(m_run - mtot), wo_ = __expf(mo - mtot);
  const float lt = l_run * w + lo * wo_;
  const float sc = w / lt;
  #pragma unroll
  for (int i = 0; i < 16; ++i) Oacc[i] *= sc;

  float* Obuf = reinterpret_cast<float*>(smem);
  #define OFF_(G, C, X) ((G) * 4360 + (C) * 17 + (X))
  if (par == 1) {
    #pragma unroll
    for (int cs = 0; cs < 16; ++cs)
      #pragma unroll
      for (int r = 0; r < 4; ++r)
        Obuf[OFF_(g, cs * 16 + gg * 4 + r, x)] = Oacc[cs][r];
  }
  __syncthreads();
  if (par == 0) {
    #pragma unroll
    for (int cs = 0; cs < 16; ++cs)
      #pragma unroll
      for (int r = 0; r < 4; ++r)
        Obuf[OFF_(g, cs * 16 + gg * 4 + r, x)] += Oacc[cs][r];
  }
  __syncthreads();
  const int n_loc = tid & 63, cq = tid >> 6;
  const int g2 = n_loc >> 4, x2 = n_loc & 15, c0 = cq * 32;
  alignas(16) u32 wds[16];
  #pragma unroll
  for (int j = 0; j < 16; ++j)
    wds[j] = pkh(Obuf[OFF_(g2, c0 + 2 * j, x2)], Obuf[OFF_(g2, c0 + 2 * j + 1, x2)]);
  u16* dst = AVt + ((size_t)b * NPIX + qb + n_loc) * CCH + c0;
  #pragma unroll
  for (int k = 0; k < 4; ++k)
    *reinterpret_cast<uint4*>(dst + k * 8) = *reinterpret_cast<uint4*>(&wds[k * 4]);
}

// ---------------------------------------------------------------------------
extern "C" void kernel_launch(void* const* d_in, const int* in_sizes, int n_in,
                              void* d_out, int out_size, void* d_ws, size_t ws_size,
                              hipStream_t stream) {
  const float* x_q  = (const float*)d_in[0];
  const float* x_kv = (const float*)d_in[1];
  const float* Wq = (const float*)d_in[2];
  const float* bq = (const float*)d_in[3];
  const float* Wk = (const float*)d_in[4];
  const float* bk = (const float*)d_in[5];
  const float* Wv = (const float*)d_in[6];
  const float* bv = (const float*)d_in[7];
  const float* W1 = (const float*)d_in[8];
  const float* b1 = (const float*)d_in[9];
  const float* W2 = (const float*)d_in[10];
  const float* b2 = (const float*)d_in[11];
  float* out = (float*)d_out;

  u16* ws = (u16*)d_ws;
  const size_t P = (size_t)NTOT * CCH;   // 4,194,304
  u16* xqTh  = ws;
  u16* xqTl  = ws + P;
  u16* xkvTh = ws + 2 * P;
  u16* xkvTl = ws + 3 * P;
  u16* Wp    = ws + 4 * P;               // 10 planes x 65536
  u16* Whq = Wp + 0 * 65536, *Wlq = Wp + 1 * 65536;
  u16* Whk = Wp + 2 * 65536, *Wlk = Wp + 3 * 65536;
  u16* Whv = Wp + 4 * 65536, *Wlv = Wp + 5 * 65536;
  u16* Wh1 = Wp + 6 * 65536, *Wl1 = Wp + 7 * 65536;
  u16* Wh2 = Wp + 8 * 65536, *Wl2 = Wp + 9 * 65536;
  u16* base2 = Wp + 10 * 65536;
  u16* Qhp = base2 + 0 * P;
  u16* Qlp = base2 + 1 * P;
  u16* Khp = base2 + 2 * P;
  u16* Klp = base2 + 3 * P;
  u16* Vhp = base2 + 4 * P;
  u16* AVt  = xqTh;    // xqT dead after conv-Q
  u16* HIDt = xqTl;

  prep_w<<<dim3(64, 5), 256, 0, stream>>>(Wq, Wk, Wv, W1, W2, Wp);
  transpose_split<<<dim3(64, 4, 8), 256, 0, stream>>>(
      x_q, x_kv, xqTh, xqTl, xkvTh, xkvTl);

  conv_s0<2, 0><<<dim3(256, 2), 512, 0, stream>>>(xqTh, xqTl, Whq, Wlq, bq, Qhp, Qlp);
  conv_kv<<<dim3(256, 2), 512, 0, stream>>>(
      xkvTh, xkvTl, Whk, Wlk, Whv, Wlv, bk, bv, Khp, Klp, Vhp);

  attn_mfma<<<dim3(NPIX / 64, NB), 512, 0, stream>>>(Qhp, Qlp, Khp, Klp, Vhp, AVt);

  conv_s0<1, 1><<<dim3(256, 2), 512, 0, stream>>>(AVt, nullptr, Wh1, Wl1, b1, HIDt, nullptr);
  conv_s1<1, 1><<<dim3(256, 2), 512, 0, stream>>>(Wh2, Wl2, HIDt, nullptr, b2, (void*)out);
}